// Round 1
// baseline (233.225 us; speedup 1.0000x reference)
//
#include <hip/hip_runtime.h>
#include <hip/hip_bf16.h>

// Problem sizes (fixed by the reference)
#define B_  32
#define L_  512
#define D_  512
#define H_  8
#define HD_ 64
#define M_  (B_*L_)   // 16384

typedef __attribute__((ext_vector_type(8))) short bf16x8;   // 8 bf16 (4 VGPRs)
typedef __attribute__((ext_vector_type(4))) short bf16x4;
typedef __attribute__((ext_vector_type(4))) float f32x4;

__device__ __forceinline__ short f2bf(float f) {
  union { float f; unsigned u; } x; x.f = f;
  unsigned r = x.u + 0x7FFFu + ((x.u >> 16) & 1u);   // RNE truncation
  return (short)(r >> 16);
}

// --------------------------------------------------------------------------
// Weight transpose + convert: wt[w][n][k] = bf16(W_w[k][n]), w = 0..3
// (B-operand fragments of mfma_16x16x32 want k-contiguous at fixed n.)
// --------------------------------------------------------------------------
__global__ __launch_bounds__(256) void wt_kernel(
    const float* __restrict__ WQ, const float* __restrict__ WK,
    const float* __restrict__ WV, const float* __restrict__ WO,
    short* __restrict__ wt) {
  __shared__ float tile[32][33];
  int wz = blockIdx.z;
  const float* W = (wz == 0) ? WQ : (wz == 1) ? WK : (wz == 2) ? WV : WO;
  int k0 = blockIdx.y * 32, n0 = blockIdx.x * 32;
  int tr = threadIdx.x >> 5, tc = threadIdx.x & 31;
#pragma unroll
  for (int i = 0; i < 4; ++i)
    tile[tr + i * 8][tc] = W[(size_t)(k0 + tr + i * 8) * D_ + n0 + tc];
  __syncthreads();
#pragma unroll
  for (int i = 0; i < 4; ++i)
    wt[((size_t)wz * D_ + n0 + tr + i * 8) * D_ + k0 + tc] =
        f2bf(tile[tc][tr + i * 8]);
}

// --------------------------------------------------------------------------
// QKV projection GEMM: C[m][n] = X[m][:] . W[:][n] + bias[n]
// X f32 [16384x512], W via wt (bf16, n-major). grid.z = mode (0=Q,1=K,2=V).
// Output layouts: Q,K -> [b,h,l,hd] bf16; V -> [b,h,hd,l] bf16 (transposed).
// 128x128 tile, BK=32, 4 waves (2x2), 80B-padded LDS rows (2-way-free banks).
// --------------------------------------------------------------------------
__global__ __launch_bounds__(256) void gemm_qkv(
    const float* __restrict__ Xq, const float* __restrict__ Xk,
    const float* __restrict__ Xv, const short* __restrict__ wt,
    const float* __restrict__ bQ, const float* __restrict__ bK,
    const float* __restrict__ bV,
    short* __restrict__ q_ws, short* __restrict__ k_ws,
    short* __restrict__ vt_ws) {
  __shared__ __align__(16) char lds[2 * 128 * 80];
  char* Al = lds;
  char* Bl = lds + 128 * 80;

  int mode = blockIdx.z;
  const float* A = (mode == 0) ? Xq : (mode == 1) ? Xk : Xv;
  const short* WT = wt + (size_t)mode * D_ * D_;
  const float* bias = (mode == 0) ? bQ : (mode == 1) ? bK : bV;

  int m0 = blockIdx.y * 128, n0 = blockIdx.x * 128;
  int tid = threadIdx.x, lane = tid & 63, w = tid >> 6;
  int wr = w >> 1, wc = w & 1, g = lane >> 4, lr = lane & 15;

  f32x4 acc[4][4] = {};

  for (int k0 = 0; k0 < D_; k0 += 32) {
    __syncthreads();
    {  // stage A tile 128x32 f32 -> bf16 LDS (rows padded to 80B)
      int r = tid >> 3, c4 = (tid & 7) * 4;
#pragma unroll
      for (int p = 0; p < 4; ++p, r += 32) {
        const float* src = A + (size_t)(m0 + r) * D_ + k0 + c4;
        float4 af = *(const float4*)src;
        bf16x4 ab;
        ab[0] = f2bf(af.x); ab[1] = f2bf(af.y);
        ab[2] = f2bf(af.z); ab[3] = f2bf(af.w);
        *(bf16x4*)(Al + r * 80 + c4 * 2) = ab;
      }
    }
    {  // stage B tile: WT rows n0..n0+127, k0..k0+31 (already bf16, n-major)
      int r = tid >> 2, c8 = (tid & 3) * 8;
#pragma unroll
      for (int p = 0; p < 2; ++p, r += 64)
        *(bf16x8*)(Bl + r * 80 + c8 * 2) =
            *(const bf16x8*)(WT + (size_t)(n0 + r) * D_ + k0 + c8);
    }
    __syncthreads();
    bf16x8 af[4], bfr[4];
#pragma unroll
    for (int i = 0; i < 4; ++i) {
      af[i]  = *(const bf16x8*)(Al + (wr * 64 + i * 16 + lr) * 80 + g * 16);
      bfr[i] = *(const bf16x8*)(Bl + (wc * 64 + i * 16 + lr) * 80 + g * 16);
    }
#pragma unroll
    for (int mi = 0; mi < 4; ++mi)
#pragma unroll
      for (int nj = 0; nj < 4; ++nj)
        acc[mi][nj] = __builtin_amdgcn_mfma_f32_16x16x32_bf16(
            af[mi], bfr[nj], acc[mi][nj], 0, 0, 0);
  }

  // Epilogue. C layout: row = g*4 + rr, col = lr (m89-verified).
#pragma unroll
  for (int mi = 0; mi < 4; ++mi) {
#pragma unroll
    for (int nj = 0; nj < 4; ++nj) {
      int n = n0 + wc * 64 + nj * 16 + lr;
      float bb = bias[n];
      int h = n >> 6, hd = n & 63;
#pragma unroll
      for (int rr = 0; rr < 4; ++rr) {
        int m = m0 + wr * 64 + mi * 16 + g * 4 + rr;
        int b = m >> 9, l = m & 511;
        short v = f2bf(acc[mi][nj][rr] + bb);
        if (mode == 0)
          q_ws[(((size_t)b * H_ + h) * L_ + l) * HD_ + hd] = v;
        else if (mode == 1)
          k_ws[(((size_t)b * H_ + h) * L_ + l) * HD_ + hd] = v;
        else
          vt_ws[(((size_t)b * H_ + h) * HD_ + hd) * L_ + l] = v;
      }
    }
  }
}

// --------------------------------------------------------------------------
// Attention: per block = 64 q-rows of one (b,h); 4 waves x 16 rows.
// Full 512-key score row in registers; wave-local softmax; P -> swizzled LDS;
// PV MFMA with V^T read from global (L1/L2 resident).
// NOTE: the spatial/edge bias is constant along the softmax axis -> no-op.
// --------------------------------------------------------------------------
__global__ __launch_bounds__(256) void attn_kernel(
    const short* __restrict__ q_ws, const short* __restrict__ k_ws,
    const short* __restrict__ vt_ws, const float* __restrict__ mask,
    short* __restrict__ ctx_ws) {
  __shared__ __align__(16) char plds[4 * 16 * 1024];  // per-wave 16x512 bf16
  int bh = blockIdx.y;
  int b = bh >> 3, h = bh & 7;
  int tid = threadIdx.x, lane = tid & 63, w = tid >> 6;
  int g = lane >> 4, lr = lane & 15;
  int qbase = blockIdx.x * 64 + w * 16;

  const short* Qh  = q_ws  + (size_t)bh * L_ * HD_;
  const short* Kh  = k_ws  + (size_t)bh * L_ * HD_;
  const short* VTh = vt_ws + (size_t)bh * HD_ * L_;
  const float* mrow = mask + (size_t)b * L_;

  // Q fragments (A-operand): row = lr, k = g*8+j, two hd-halves
  bf16x8 aq0 = *(const bf16x8*)(Qh + (size_t)(qbase + lr) * HD_ + g * 8);
  bf16x8 aq1 = *(const bf16x8*)(Qh + (size_t)(qbase + lr) * HD_ + 32 + g * 8);

  // ---- QK^T: S[16 x 512] per wave, 32 key-tiles of 16 ----
  f32x4 s[32];
#pragma unroll
  for (int kt = 0; kt < 32; ++kt) {
    bf16x8 bk0 = *(const bf16x8*)(Kh + (size_t)(kt * 16 + lr) * HD_ + g * 8);
    bf16x8 bk1 = *(const bf16x8*)(Kh + (size_t)(kt * 16 + lr) * HD_ + 32 + g * 8);
    f32x4 a = {0.f, 0.f, 0.f, 0.f};
    a = __builtin_amdgcn_mfma_f32_16x16x32_bf16(aq0, bk0, a, 0, 0, 0);
    a = __builtin_amdgcn_mfma_f32_16x16x32_bf16(aq1, bk1, a, 0, 0, 0);
    float mb = (1.0f - mrow[kt * 16 + lr]) * -1e9f;   // mask term (k-varying)
#pragma unroll
    for (int rr = 0; rr < 4; ++rr) a[rr] = a[rr] * 0.125f + mb;  // /sqrt(64)
    s[kt] = a;
  }

  // ---- softmax over keys; per lane owns rows g*4+rr, cols lr+16*kt ----
  float mx[4], sum[4], inv[4];
#pragma unroll
  for (int rr = 0; rr < 4; ++rr) mx[rr] = -3.0e38f;
#pragma unroll
  for (int kt = 0; kt < 32; ++kt)
#pragma unroll
    for (int rr = 0; rr < 4; ++rr) mx[rr] = fmaxf(mx[rr], s[kt][rr]);
#pragma unroll
  for (int off = 1; off < 16; off <<= 1)
#pragma unroll
    for (int rr = 0; rr < 4; ++rr)
      mx[rr] = fmaxf(mx[rr], __shfl_xor(mx[rr], off, 64));
#pragma unroll
  for (int rr = 0; rr < 4; ++rr) sum[rr] = 0.f;

  // write P (bf16) into this wave's LDS tile, XOR-swizzled (G4: stride-1KB
  // rows are a 16-way conflict otherwise); swizzle: byte ^= (row&7)<<4
  char* pw = plds + (size_t)w * 16384;
#pragma unroll
  for (int kt = 0; kt < 32; ++kt) {
    int col2 = (kt * 16 + lr) * 2;
#pragma unroll
    for (int rr = 0; rr < 4; ++rr) {
      float p = __expf(s[kt][rr] - mx[rr]);
      sum[rr] += p;
      int row = g * 4 + rr;
      *(short*)(pw + row * 1024 + (col2 ^ ((row & 7) << 4))) = f2bf(p);
    }
  }
#pragma unroll
  for (int off = 1; off < 16; off <<= 1)
#pragma unroll
    for (int rr = 0; rr < 4; ++rr) sum[rr] += __shfl_xor(sum[rr], off, 64);
#pragma unroll
  for (int rr = 0; rr < 4; ++rr) inv[rr] = 1.0f / sum[rr];

  __syncthreads();  // also serves as lgkmcnt drain for own-wave P writes

  // ---- PV: ctx[16 x 64] = P[16 x 512] @ V[512 x 64] ----
  f32x4 c[4] = {};
  int swz = (lr & 7) << 4;
#pragma unroll
  for (int kt32 = 0; kt32 < 16; ++kt32) {
    // A-frag of P: row = lr, k = kt32*32 + g*8 (swizzle-matched 16B read)
    bf16x8 ap = *(const bf16x8*)(pw + lr * 1024 + ((kt32 * 64 + g * 16) ^ swz));
#pragma unroll
    for (int nt = 0; nt < 4; ++nt) {
      // B-frag of V: n = nt*16+lr (hd), k = key -> V^T row hd, k-contiguous
      bf16x8 bv = *(const bf16x8*)(VTh + (size_t)(nt * 16 + lr) * L_ +
                                   kt32 * 32 + g * 8);
      c[nt] = __builtin_amdgcn_mfma_f32_16x16x32_bf16(ap, bv, c[nt], 0, 0, 0);
    }
  }

  // epilogue: ctx_ws[b][l][h][hd] (row-major [16384][512] for the out-GEMM)
#pragma unroll
  for (int nt = 0; nt < 4; ++nt) {
    int hd = nt * 16 + lr;
#pragma unroll
    for (int rr = 0; rr < 4; ++rr) {
      int qrow = qbase + g * 4 + rr;
      ctx_ws[(((size_t)b * L_ + qrow) * H_ + h) * HD_ + hd] =
          f2bf(c[nt][rr] * inv[rr]);
    }
  }
}

// --------------------------------------------------------------------------
// Output GEMM: out[m][n] = ctx[m][:] . WO[:][n] + bO[n]   (f32 out)
// --------------------------------------------------------------------------
__global__ __launch_bounds__(256) void gemm_out(
    const short* __restrict__ ctx, const short* __restrict__ wt3,
    const float* __restrict__ bO, float* __restrict__ out) {
  __shared__ __align__(16) char lds[2 * 128 * 80];
  char* Al = lds;
  char* Bl = lds + 128 * 80;
  int m0 = blockIdx.y * 128, n0 = blockIdx.x * 128;
  int tid = threadIdx.x, lane = tid & 63, w = tid >> 6;
  int wr = w >> 1, wc = w & 1, g = lane >> 4, lr = lane & 15;
  f32x4 acc[4][4] = {};

  for (int k0 = 0; k0 < D_; k0 += 32) {
    __syncthreads();
    {
      int r = tid >> 2, c8 = (tid & 3) * 8;
#pragma unroll
      for (int p = 0; p < 2; ++p, r += 64)
        *(bf16x8*)(Al + r * 80 + c8 * 2) =
            *(const bf16x8*)(ctx + (size_t)(m0 + r) * D_ + k0 + c8);
    }
    {
      int r = tid >> 2, c8 = (tid & 3) * 8;
#pragma unroll
      for (int p = 0; p < 2; ++p, r += 64)
        *(bf16x8*)(Bl + r * 80 + c8 * 2) =
            *(const bf16x8*)(wt3 + (size_t)(n0 + r) * D_ + k0 + c8);
    }
    __syncthreads();
    bf16x8 af[4], bfr[4];
#pragma unroll
    for (int i = 0; i < 4; ++i) {
      af[i]  = *(const bf16x8*)(Al + (wr * 64 + i * 16 + lr) * 80 + g * 16);
      bfr[i] = *(const bf16x8*)(Bl + (wc * 64 + i * 16 + lr) * 80 + g * 16);
    }
#pragma unroll
    for (int mi = 0; mi < 4; ++mi)
#pragma unroll
      for (int nj = 0; nj < 4; ++nj)
        acc[mi][nj] = __builtin_amdgcn_mfma_f32_16x16x32_bf16(
            af[mi], bfr[nj], acc[mi][nj], 0, 0, 0);
  }
#pragma unroll
  for (int mi = 0; mi < 4; ++mi) {
#pragma unroll
    for (int nj = 0; nj < 4; ++nj) {
      int n = n0 + wc * 64 + nj * 16 + lr;
      float bb = bO[n];
#pragma unroll
      for (int rr = 0; rr < 4; ++rr) {
        int m = m0 + wr * 64 + mi * 16 + g * 4 + rr;
        out[(size_t)m * D_ + n] = acc[mi][nj][rr] + bb;
      }
    }
  }
}

// --------------------------------------------------------------------------
extern "C" void kernel_launch(void* const* d_in, const int* in_sizes, int n_in,
                              void* d_out, int out_size, void* d_ws,
                              size_t ws_size, hipStream_t stream) {
  const float* query = (const float*)d_in[0];
  const float* key   = (const float*)d_in[1];
  const float* value = (const float*)d_in[2];
  const float* mask  = (const float*)d_in[3];
  // d_in[4..8]: edge_attr / path_* — unused: the resulting bias is constant
  // along the softmax axis, so it cancels exactly in softmax.
  const float* WQ = (const float*)d_in[9];
  const float* bQ = (const float*)d_in[10];
  const float* WK = (const float*)d_in[11];
  const float* bK = (const float*)d_in[12];
  const float* WV = (const float*)d_in[13];
  const float* bV = (const float*)d_in[14];
  const float* WO = (const float*)d_in[15];
  const float* bO = (const float*)d_in[16];

  // ws layout (shorts): wt[4*512*512] | Q | K | V^T | ctx  (each 8388608)
  short* ws  = (short*)d_ws;
  short* wt  = ws;
  short* q   = ws + 1048576;
  short* k   = q + 8388608;
  short* vt  = k + 8388608;
  short* ctx = vt + 8388608;   // total 34,603,008 shorts = 69.2 MB
  float* out = (float*)d_out;

  wt_kernel<<<dim3(16, 16, 4), 256, 0, stream>>>(WQ, WK, WV, WO, wt);
  gemm_qkv<<<dim3(4, 128, 3), 256, 0, stream>>>(query, key, value, wt,
                                                bQ, bK, bV, q, k, vt);
  attn_kernel<<<dim3(8, 256), 256, 0, stream>>>(q, k, vt, mask, ctx);
  gemm_out<<<dim3(4, 128), 256, 0, stream>>>(ctx, wt + 3 * 262144, bO, out);
}

// Round 2
// 207.349 us; speedup vs baseline: 1.1248x; 1.1248x over previous
//
#include <hip/hip_runtime.h>
#include <hip/hip_bf16.h>

// Problem sizes (fixed by the reference)
#define B_  32
#define L_  512
#define D_  512
#define H_  8
#define HD_ 64

typedef __attribute__((ext_vector_type(8))) short bf16x8;   // 8 bf16 (4 VGPRs)
typedef __attribute__((ext_vector_type(4))) short bf16x4;
typedef __attribute__((ext_vector_type(4))) float f32x4;

__device__ __forceinline__ short f2bf(float f) {
  union { float f; unsigned u; } x; x.f = f;
  unsigned r = x.u + 0x7FFFu + ((x.u >> 16) & 1u);   // RNE truncation
  return (short)(r >> 16);
}

// async global->LDS, 16B per lane; dest base must be wave-uniform (HW adds lane*16)
__device__ __forceinline__ void gll16(const void* g, void* l) {
  __builtin_amdgcn_global_load_lds(
      (const __attribute__((address_space(1))) unsigned int*)g,
      (__attribute__((address_space(3))) unsigned int*)l, 16, 0, 0);
}

// 8x f32 -> bf16x8 via v_cvt_pk_bf16_f32 (compiler lowers __float22bfloat162_rn)
__device__ __forceinline__ bf16x8 cvt8(f32x4 a, f32x4 b) {
  union { __hip_bfloat162 h[4]; bf16x8 v; } u;
  u.h[0] = __float22bfloat162_rn(float2{a[0], a[1]});
  u.h[1] = __float22bfloat162_rn(float2{a[2], a[3]});
  u.h[2] = __float22bfloat162_rn(float2{b[0], b[1]});
  u.h[3] = __float22bfloat162_rn(float2{b[2], b[3]});
  return u.v;
}

// same-wave LDS write->read ordering fence (rule 18: sched_barrier after asm waitcnt)
#define DS_FENCE() do { asm volatile("s_waitcnt lgkmcnt(0)" ::: "memory"); \
                        __builtin_amdgcn_sched_barrier(0); } while (0)

// --------------------------------------------------------------------------
// Weight transpose + convert: wt[w][n][k] = bf16(W_w[k][n]), w = 0..3
// --------------------------------------------------------------------------
__global__ __launch_bounds__(256) void wt_kernel(
    const float* __restrict__ WQ, const float* __restrict__ WK,
    const float* __restrict__ WV, const float* __restrict__ WO,
    short* __restrict__ wt) {
  __shared__ float tile[32][33];
  int wz = blockIdx.z;
  const float* W = (wz == 0) ? WQ : (wz == 1) ? WK : (wz == 2) ? WV : WO;
  int k0 = blockIdx.y * 32, n0 = blockIdx.x * 32;
  int tr = threadIdx.x >> 5, tc = threadIdx.x & 31;
#pragma unroll
  for (int i = 0; i < 4; ++i)
    tile[tr + i * 8][tc] = W[(size_t)(k0 + tr + i * 8) * D_ + n0 + tc];
  __syncthreads();
#pragma unroll
  for (int i = 0; i < 4; ++i)
    wt[((size_t)wz * D_ + n0 + tr + i * 8) * D_ + k0 + tc] =
        f2bf(tile[tc][tr + i * 8]);
}

// --------------------------------------------------------------------------
// QKV projection GEMM, BK=64, global_load_lds staging (A kept f32 in LDS,
// converted at fragment load), chunk-XOR swizzled LDS (pre-swizzled source).
// Output layouts: Q,K -> [b,h,l,hd] bf16; V -> [b,h,hd,l] bf16.
// --------------------------------------------------------------------------
__global__ __launch_bounds__(256) void gemm_qkv(
    const float* __restrict__ Xq, const float* __restrict__ Xk,
    const float* __restrict__ Xv, const short* __restrict__ wt,
    const float* __restrict__ bQ, const float* __restrict__ bK,
    const float* __restrict__ bV,
    short* __restrict__ q_ws, short* __restrict__ k_ws,
    short* __restrict__ vt_ws) {
  __shared__ __align__(16) char lds[49152];
  char* Al = lds;           // f32 A tile [128][64], 256B rows, 16B-chunk swizzle
  char* Bl = lds + 32768;   // bf16 B tile [128][64], 128B rows, 16B-chunk swizzle

  int mode = blockIdx.z;
  const float* A = (mode == 0) ? Xq : (mode == 1) ? Xk : Xv;
  const short* WT = wt + (size_t)mode * D_ * D_;
  const float* bias = (mode == 0) ? bQ : (mode == 1) ? bK : bV;

  // XCD swizzle: the 4 n-tiles sharing the same A-rows land on one XCD.
  int wgid = blockIdx.x + 4 * blockIdx.y;   // 0..511 (512 % 8 == 0: bijective)
  int rr_ = wgid >> 3;
  int m0 = ((wgid & 7) * 16 + (rr_ >> 2)) * 128;
  int n0 = (rr_ & 3) * 128;

  int tid = threadIdx.x, lane = tid & 63, w = tid >> 6;
  int wr = w >> 1, wc = w & 1, g = lane >> 4, lr = lane & 15;

  f32x4 acc[4][4] = {};

  for (int k0 = 0; k0 < D_; k0 += 64) {
    __syncthreads();
    // stage A: 32 KB = 32 wave-issues of 1KB; slot s of row holds chunk s^row
#pragma unroll
    for (int j = 0; j < 8; ++j) {
      int e = w * 8 + j;
      int row = e * 4 + (lane >> 4);
      int chunk = (lane & 15) ^ (row & 15);
      gll16(A + (size_t)(m0 + row) * D_ + k0 + chunk * 4, Al + e * 1024);
    }
    // stage B: 16 KB = 16 wave-issues; row&7 == lane>>3 within each issue
#pragma unroll
    for (int j = 0; j < 4; ++j) {
      int e = w * 4 + j;
      int row = e * 8 + (lane >> 3);
      int chunk = (lane & 7) ^ (lane >> 3);
      gll16(WT + (size_t)(n0 + row) * D_ + k0 + chunk * 8, Bl + e * 1024);
    }
    __syncthreads();   // drains vmcnt -> tiles ready
#pragma unroll
    for (int kk = 0; kk < 2; ++kk) {
      bf16x8 af[4], bf_[4];
#pragma unroll
      for (int i = 0; i < 4; ++i) {
        int row = wr * 64 + i * 16 + lr;            // row & 15 == lr
        int o0 = ((kk * 8 + g * 2) ^ lr) << 4;
        int o1 = ((kk * 8 + g * 2 + 1) ^ lr) << 4;
        f32x4 lo = *(const f32x4*)(Al + row * 256 + o0);
        f32x4 hi = *(const f32x4*)(Al + row * 256 + o1);
        af[i] = cvt8(lo, hi);
      }
#pragma unroll
      for (int i = 0; i < 4; ++i) {
        int row = wc * 64 + i * 16 + lr;            // row & 7 == lr & 7
        bf_[i] = *(const bf16x8*)(Bl + row * 128 +
                                  (((kk * 4 + g) ^ (lr & 7)) << 4));
      }
#pragma unroll
      for (int mi = 0; mi < 4; ++mi)
#pragma unroll
        for (int nj = 0; nj < 4; ++nj)
          acc[mi][nj] = __builtin_amdgcn_mfma_f32_16x16x32_bf16(
              af[mi], bf_[nj], acc[mi][nj], 0, 0, 0);
    }
  }

  // Epilogue. C layout: row = g*4 + rr, col = lr (m89-verified).
#pragma unroll
  for (int mi = 0; mi < 4; ++mi) {
#pragma unroll
    for (int nj = 0; nj < 4; ++nj) {
      int n = n0 + wc * 64 + nj * 16 + lr;
      float bb = bias[n];
      int h = n >> 6, hd = n & 63;
#pragma unroll
      for (int rr = 0; rr < 4; ++rr) {
        int m = m0 + wr * 64 + mi * 16 + g * 4 + rr;
        int b = m >> 9, l = m & 511;
        short v = f2bf(acc[mi][nj][rr] + bb);
        if (mode == 0)
          q_ws[(((size_t)b * H_ + h) * L_ + l) * HD_ + hd] = v;
        else if (mode == 1)
          k_ws[(((size_t)b * H_ + h) * L_ + l) * HD_ + hd] = v;
        else
          vt_ws[(((size_t)b * H_ + h) * HD_ + hd) * L_ + l] = v;
      }
    }
  }
}

// --------------------------------------------------------------------------
// Attention: block = 64 q-rows of one (b,h); 4 waves x 16 rows; no barriers.
// Two-pass PV halves P-LDS to 8KB/wave (32KB/block -> 4+ blocks/CU).
// XCD-bijective swizzle: all 8 q-blocks of a (b,h) land on one XCD's L2.
// --------------------------------------------------------------------------
__global__ __launch_bounds__(256) void attn_kernel(
    const short* __restrict__ q_ws, const short* __restrict__ k_ws,
    const short* __restrict__ vt_ws, const float* __restrict__ mask,
    short* __restrict__ ctx_ws) {
  __shared__ __align__(16) char plds[4 * 8192];   // per-wave 16x256 bf16 tile
  int wg = blockIdx.x;                            // 2048 blocks, 2048%8==0
  int bh   = (wg & 7) * 32 + (wg >> 6);           // 32 heads per XCD
  int qblk = (wg >> 3) & 7;
  int b = bh >> 3, h = bh & 7;
  int tid = threadIdx.x, lane = tid & 63, w = tid >> 6;
  int g = lane >> 4, lr = lane & 15;
  int qbase = qblk * 64 + w * 16;

  const short* Qh  = q_ws  + (size_t)bh * L_ * HD_;
  const short* Kh  = k_ws  + (size_t)bh * L_ * HD_;
  const short* VTh = vt_ws + (size_t)bh * HD_ * L_;
  const float* mrow = mask + (size_t)b * L_;

  bf16x8 aq0 = *(const bf16x8*)(Qh + (size_t)(qbase + lr) * HD_ + g * 8);
  bf16x8 aq1 = *(const bf16x8*)(Qh + (size_t)(qbase + lr) * HD_ + 32 + g * 8);

  // ---- QK^T: S[16 x 512] per wave ----
  f32x4 s[32];
#pragma unroll
  for (int kt = 0; kt < 32; ++kt) {
    bf16x8 bk0 = *(const bf16x8*)(Kh + (size_t)(kt * 16 + lr) * HD_ + g * 8);
    bf16x8 bk1 = *(const bf16x8*)(Kh + (size_t)(kt * 16 + lr) * HD_ + 32 + g * 8);
    f32x4 a = {0.f, 0.f, 0.f, 0.f};
    a = __builtin_amdgcn_mfma_f32_16x16x32_bf16(aq0, bk0, a, 0, 0, 0);
    a = __builtin_amdgcn_mfma_f32_16x16x32_bf16(aq1, bk1, a, 0, 0, 0);
    float mb = (1.0f - mrow[kt * 16 + lr]) * -1e9f;
#pragma unroll
    for (int rr = 0; rr < 4; ++rr) a[rr] = a[rr] * 0.125f + mb;
    s[kt] = a;
  }

  // ---- row max (lane owns rows g*4+rr, cols lr+16*kt) ----
  float mx[4], sum[4] = {0.f, 0.f, 0.f, 0.f}, inv[4];
#pragma unroll
  for (int rr = 0; rr < 4; ++rr) mx[rr] = -3.0e38f;
#pragma unroll
  for (int kt = 0; kt < 32; ++kt)
#pragma unroll
    for (int rr = 0; rr < 4; ++rr) mx[rr] = fmaxf(mx[rr], s[kt][rr]);
#pragma unroll
  for (int off = 1; off < 16; off <<= 1)
#pragma unroll
    for (int rr = 0; rr < 4; ++rr)
      mx[rr] = fmaxf(mx[rr], __shfl_xor(mx[rr], off, 64));

  // ---- two-pass: P-half -> LDS (8KB, XOR-swizzled) -> PV accumulate ----
  char* pw = plds + (size_t)w * 8192;
  f32x4 c[4] = {};
#pragma unroll
  for (int half = 0; half < 2; ++half) {
#pragma unroll
    for (int kt = 0; kt < 16; ++kt) {
      int ktg = half * 16 + kt;
      int col2 = (kt * 16 + lr) * 2;
#pragma unroll
      for (int rr = 0; rr < 4; ++rr) {
        float p = __expf(s[ktg][rr] - mx[rr]);
        sum[rr] += p;
        int row = g * 4 + rr;
        *(short*)(pw + row * 512 + (col2 ^ ((row & 7) << 4))) = f2bf(p);
      }
    }
    DS_FENCE();   // writes visible before transposed reads
#pragma unroll
    for (int kt32 = 0; kt32 < 8; ++kt32) {
      bf16x8 ap = *(const bf16x8*)(pw + lr * 512 +
                                   ((kt32 * 64 + g * 16) ^ ((lr & 7) << 4)));
#pragma unroll
      for (int nt = 0; nt < 4; ++nt) {
        bf16x8 bv = *(const bf16x8*)(VTh + (size_t)(nt * 16 + lr) * L_ +
                                     half * 256 + kt32 * 32 + g * 8);
        c[nt] = __builtin_amdgcn_mfma_f32_16x16x32_bf16(ap, bv, c[nt], 0, 0, 0);
      }
    }
    DS_FENCE();   // reads done before next half's writes (WAR)
  }

#pragma unroll
  for (int off = 1; off < 16; off <<= 1)
#pragma unroll
    for (int rr = 0; rr < 4; ++rr) sum[rr] += __shfl_xor(sum[rr], off, 64);
#pragma unroll
  for (int rr = 0; rr < 4; ++rr) inv[rr] = 1.0f / sum[rr];

  // epilogue: ctx_ws[b][l][h][hd] (row-major [16384][512] for the out-GEMM)
#pragma unroll
  for (int nt = 0; nt < 4; ++nt) {
    int hd = nt * 16 + lr;
#pragma unroll
    for (int rr = 0; rr < 4; ++rr) {
      int qrow = qbase + g * 4 + rr;
      ctx_ws[(((size_t)b * L_ + qrow) * H_ + h) * HD_ + hd] =
          f2bf(c[nt][rr] * inv[rr]);
    }
  }
}

// --------------------------------------------------------------------------
// Output GEMM (bf16 x bf16 -> f32), BK=64, global_load_lds, swizzled LDS.
// --------------------------------------------------------------------------
__global__ __launch_bounds__(256) void gemm_out(
    const short* __restrict__ ctx, const short* __restrict__ wt3,
    const float* __restrict__ bO, float* __restrict__ out) {
  __shared__ __align__(16) char lds[32768];
  char* Al = lds;
  char* Bl = lds + 16384;
  int wgid = blockIdx.x + 4 * blockIdx.y;
  int rr_ = wgid >> 3;
  int m0 = ((wgid & 7) * 16 + (rr_ >> 2)) * 128;
  int n0 = (rr_ & 3) * 128;
  int tid = threadIdx.x, lane = tid & 63, w = tid >> 6;
  int wr = w >> 1, wc = w & 1, g = lane >> 4, lr = lane & 15;
  f32x4 acc[4][4] = {};

  for (int k0 = 0; k0 < D_; k0 += 64) {
    __syncthreads();
#pragma unroll
    for (int j = 0; j < 4; ++j) {
      int e = w * 4 + j;
      int row = e * 8 + (lane >> 3);
      int chunk = (lane & 7) ^ (lane >> 3);
      gll16(ctx + (size_t)(m0 + row) * D_ + k0 + chunk * 8, Al + e * 1024);
    }
#pragma unroll
    for (int j = 0; j < 4; ++j) {
      int e = w * 4 + j;
      int row = e * 8 + (lane >> 3);
      int chunk = (lane & 7) ^ (lane >> 3);
      gll16(wt3 + (size_t)(n0 + row) * D_ + k0 + chunk * 8, Bl + e * 1024);
    }
    __syncthreads();
#pragma unroll
    for (int kk = 0; kk < 2; ++kk) {
      bf16x8 af[4], bf_[4];
#pragma unroll
      for (int i = 0; i < 4; ++i) {
        int row = wr * 64 + i * 16 + lr;
        af[i] = *(const bf16x8*)(Al + row * 128 +
                                 (((kk * 4 + g) ^ (lr & 7)) << 4));
      }
#pragma unroll
      for (int i = 0; i < 4; ++i) {
        int row = wc * 64 + i * 16 + lr;
        bf_[i] = *(const bf16x8*)(Bl + row * 128 +
                                  (((kk * 4 + g) ^ (lr & 7)) << 4));
      }
#pragma unroll
      for (int mi = 0; mi < 4; ++mi)
#pragma unroll
        for (int nj = 0; nj < 4; ++nj)
          acc[mi][nj] = __builtin_amdgcn_mfma_f32_16x16x32_bf16(
              af[mi], bf_[nj], acc[mi][nj], 0, 0, 0);
    }
  }
#pragma unroll
  for (int mi = 0; mi < 4; ++mi) {
#pragma unroll
    for (int nj = 0; nj < 4; ++nj) {
      int n = n0 + wc * 64 + nj * 16 + lr;
      float bb = bO[n];
#pragma unroll
      for (int rr = 0; rr < 4; ++rr) {
        int m = m0 + wr * 64 + mi * 16 + g * 4 + rr;
        out[(size_t)m * D_ + n] = acc[mi][nj][rr] + bb;
      }
    }
  }
}

// --------------------------------------------------------------------------
extern "C" void kernel_launch(void* const* d_in, const int* in_sizes, int n_in,
                              void* d_out, int out_size, void* d_ws,
                              size_t ws_size, hipStream_t stream) {
  const float* query = (const float*)d_in[0];
  const float* key   = (const float*)d_in[1];
  const float* value = (const float*)d_in[2];
  const float* mask  = (const float*)d_in[3];
  // d_in[4..8]: edge/path inputs — bias is constant along the softmax axis,
  // so it cancels exactly; unused.
  const float* WQ = (const float*)d_in[9];
  const float* bQ = (const float*)d_in[10];
  const float* WK = (const float*)d_in[11];
  const float* bK = (const float*)d_in[12];
  const float* WV = (const float*)d_in[13];
  const float* bV = (const float*)d_in[14];
  const float* WO = (const float*)d_in[15];
  const float* bO = (const float*)d_in[16];

  short* ws  = (short*)d_ws;
  short* wt  = ws;
  short* q   = ws + 1048576;
  short* k   = q + 8388608;
  short* vt  = k + 8388608;
  short* ctx = vt + 8388608;   // total 34,603,008 shorts = 69.2 MB
  float* out = (float*)d_out;

  wt_kernel<<<dim3(16, 16, 4), 256, 0, stream>>>(WQ, WK, WV, WO, wt);
  gemm_qkv<<<dim3(4, 128, 3), 256, 0, stream>>>(query, key, value, wt,
                                                bQ, bK, bV, q, k, vt);
  attn_kernel<<<2048, 256, 0, stream>>>(q, k, vt, mask, ctx);
  gemm_out<<<dim3(4, 128), 256, 0, stream>>>(ctx, wt + 3 * 262144, bO, out);
}

// Round 3
// 135.460 us; speedup vs baseline: 1.7217x; 1.5307x over previous
//
#include <hip/hip_runtime.h>
#include <hip/hip_bf16.h>

// Problem sizes (fixed by the reference)
#define B_  32
#define L_  512
#define D_  512
#define H_  8
#define HD_ 64

typedef __attribute__((ext_vector_type(8))) short bf16x8;   // 8 bf16 (4 VGPRs)
typedef __attribute__((ext_vector_type(4))) short bf16x4;
typedef __attribute__((ext_vector_type(4))) float f32x4;

__device__ __forceinline__ short f2bf(float f) {
  union { float f; unsigned u; } x; x.f = f;
  unsigned r = x.u + 0x7FFFu + ((x.u >> 16) & 1u);   // RNE truncation
  return (short)(r >> 16);
}

// async global->LDS, 16B per lane; dest base must be wave-uniform (HW adds lane*16)
__device__ __forceinline__ void gll16(const void* g, void* l) {
  __builtin_amdgcn_global_load_lds(
      (const __attribute__((address_space(1))) unsigned int*)g,
      (__attribute__((address_space(3))) unsigned int*)l, 16, 0, 0);
}

// 8x f32 -> bf16x8 via v_cvt_pk_bf16_f32 (compiler lowers __float22bfloat162_rn)
__device__ __forceinline__ bf16x8 cvt8(f32x4 a, f32x4 b) {
  union { __hip_bfloat162 h[4]; bf16x8 v; } u;
  u.h[0] = __float22bfloat162_rn(float2{a[0], a[1]});
  u.h[1] = __float22bfloat162_rn(float2{a[2], a[3]});
  u.h[2] = __float22bfloat162_rn(float2{b[0], b[1]});
  u.h[3] = __float22bfloat162_rn(float2{b[2], b[3]});
  return u.v;
}

// same-wave LDS write->read ordering fence (rule 18: sched_barrier after asm waitcnt)
#define DS_FENCE() do { asm volatile("s_waitcnt lgkmcnt(0)" ::: "memory"); \
                        __builtin_amdgcn_sched_barrier(0); } while (0)

// --------------------------------------------------------------------------
// Weight transpose + convert: wt[w][n][k] = bf16(W_w[k][n]), w = 0..3
// --------------------------------------------------------------------------
__global__ __launch_bounds__(256) void wt_kernel(
    const float* __restrict__ WQ, const float* __restrict__ WK,
    const float* __restrict__ WV, const float* __restrict__ WO,
    short* __restrict__ wt) {
  __shared__ float tile[32][33];
  int wz = blockIdx.z;
  const float* W = (wz == 0) ? WQ : (wz == 1) ? WK : (wz == 2) ? WV : WO;
  int k0 = blockIdx.y * 32, n0 = blockIdx.x * 32;
  int tr = threadIdx.x >> 5, tc = threadIdx.x & 31;
#pragma unroll
  for (int i = 0; i < 4; ++i)
    tile[tr + i * 8][tc] = W[(size_t)(k0 + tr + i * 8) * D_ + n0 + tc];
  __syncthreads();
#pragma unroll
  for (int i = 0; i < 4; ++i)
    wt[((size_t)wz * D_ + n0 + tr + i * 8) * D_ + k0 + tc] =
        f2bf(tile[tc][tr + i * 8]);
}

// --------------------------------------------------------------------------
// QKV projection GEMM, BK=64, global_load_lds staging (A kept f32 in LDS,
// converted at fragment load), chunk-XOR swizzled LDS (pre-swizzled source).
// Output layouts: Q,K -> [b,h,l,hd] bf16; V -> [b,h,hd,l] bf16.
// --------------------------------------------------------------------------
__global__ __launch_bounds__(256) void gemm_qkv(
    const float* __restrict__ Xq, const float* __restrict__ Xk,
    const float* __restrict__ Xv, const short* __restrict__ wt,
    const float* __restrict__ bQ, const float* __restrict__ bK,
    const float* __restrict__ bV,
    short* __restrict__ q_ws, short* __restrict__ k_ws,
    short* __restrict__ vt_ws) {
  __shared__ __align__(16) char lds[49152];
  char* Al = lds;           // f32 A tile [128][64], 256B rows, 16B-chunk swizzle
  char* Bl = lds + 32768;   // bf16 B tile [128][64], 128B rows, 16B-chunk swizzle

  int mode = blockIdx.z;
  const float* A = (mode == 0) ? Xq : (mode == 1) ? Xk : Xv;
  const short* WT = wt + (size_t)mode * D_ * D_;
  const float* bias = (mode == 0) ? bQ : (mode == 1) ? bK : bV;

  // XCD swizzle: the 4 n-tiles sharing the same A-rows land on one XCD.
  int wgid = blockIdx.x + 4 * blockIdx.y;   // 0..511 (512 % 8 == 0: bijective)
  int rr_ = wgid >> 3;
  int m0 = ((wgid & 7) * 16 + (rr_ >> 2)) * 128;
  int n0 = (rr_ & 3) * 128;

  int tid = threadIdx.x, lane = tid & 63, w = tid >> 6;
  int wr = w >> 1, wc = w & 1, g = lane >> 4, lr = lane & 15;

  f32x4 acc[4][4] = {};

  for (int k0 = 0; k0 < D_; k0 += 64) {
    __syncthreads();
    // stage A: 32 KB = 32 wave-issues of 1KB; slot s of row holds chunk s^row
#pragma unroll
    for (int j = 0; j < 8; ++j) {
      int e = w * 8 + j;
      int row = e * 4 + (lane >> 4);
      int chunk = (lane & 15) ^ (row & 15);
      gll16(A + (size_t)(m0 + row) * D_ + k0 + chunk * 4, Al + e * 1024);
    }
    // stage B: 16 KB = 16 wave-issues; row&7 == lane>>3 within each issue
#pragma unroll
    for (int j = 0; j < 4; ++j) {
      int e = w * 4 + j;
      int row = e * 8 + (lane >> 3);
      int chunk = (lane & 7) ^ (lane >> 3);
      gll16(WT + (size_t)(n0 + row) * D_ + k0 + chunk * 8, Bl + e * 1024);
    }
    __syncthreads();   // drains vmcnt -> tiles ready
#pragma unroll
    for (int kk = 0; kk < 2; ++kk) {
      bf16x8 af[4], bf_[4];
#pragma unroll
      for (int i = 0; i < 4; ++i) {
        int row = wr * 64 + i * 16 + lr;            // row & 15 == lr
        int o0 = ((kk * 8 + g * 2) ^ lr) << 4;
        int o1 = ((kk * 8 + g * 2 + 1) ^ lr) << 4;
        f32x4 lo = *(const f32x4*)(Al + row * 256 + o0);
        f32x4 hi = *(const f32x4*)(Al + row * 256 + o1);
        af[i] = cvt8(lo, hi);
      }
#pragma unroll
      for (int i = 0; i < 4; ++i) {
        int row = wc * 64 + i * 16 + lr;            // row & 7 == lr & 7
        bf_[i] = *(const bf16x8*)(Bl + row * 128 +
                                  (((kk * 4 + g) ^ (lr & 7)) << 4));
      }
#pragma unroll
      for (int mi = 0; mi < 4; ++mi)
#pragma unroll
        for (int nj = 0; nj < 4; ++nj)
          acc[mi][nj] = __builtin_amdgcn_mfma_f32_16x16x32_bf16(
              af[mi], bf_[nj], acc[mi][nj], 0, 0, 0);
    }
  }

  // Epilogue. C layout: row = g*4 + rr, col = lr (m89-verified).
#pragma unroll
  for (int mi = 0; mi < 4; ++mi) {
#pragma unroll
    for (int nj = 0; nj < 4; ++nj) {
      int n = n0 + wc * 64 + nj * 16 + lr;
      float bb = bias[n];
      int h = n >> 6, hd = n & 63;
#pragma unroll
      for (int rr = 0; rr < 4; ++rr) {
        int m = m0 + wr * 64 + mi * 16 + g * 4 + rr;
        int b = m >> 9, l = m & 511;
        short v = f2bf(acc[mi][nj][rr] + bb);
        if (mode == 0)
          q_ws[(((size_t)b * H_ + h) * L_ + l) * HD_ + hd] = v;
        else if (mode == 1)
          k_ws[(((size_t)b * H_ + h) * L_ + l) * HD_ + hd] = v;
        else
          vt_ws[(((size_t)b * H_ + h) * HD_ + hd) * L_ + l] = v;
      }
    }
  }
}

// --------------------------------------------------------------------------
// Attention, flash-style: block = 64 q-rows of one (b,h); 4 waves x 16 rows.
// 8 chunks of 64 keys; K/V chunk staged in LDS via global_load_lds (shared by
// all 4 waves, double-buffered, XOR-swizzled via pre-swizzled source), online
// softmax (small register state -> 4 waves/SIMD occupancy target).
// LDS: K 2x8KB | V^T 2x8KB | P 4x2KB = 40KB -> 4 blocks/CU.
// --------------------------------------------------------------------------
__global__ __launch_bounds__(256, 4) void attn_kernel(
    const short* __restrict__ q_ws, const short* __restrict__ k_ws,
    const short* __restrict__ vt_ws, const float* __restrict__ mask,
    short* __restrict__ ctx_ws) {
  __shared__ __align__(16) char lds[40960];
  int wg = blockIdx.x;                            // 2048 blocks, 2048%8==0
  int bh   = (wg & 7) * 32 + (wg >> 6);           // XCD-bijective: 32 heads/XCD
  int qblk = (wg >> 3) & 7;
  int b = bh >> 3, h = bh & 7;
  int tid = threadIdx.x, lane = tid & 63, w = tid >> 6;
  int g = lane >> 4, lr = lane & 15;
  char* Pl = lds + 32768 + w * 2048;              // per-wave P tile 16x64 bf16
  int qbase = qblk * 64 + w * 16;

  const short* Qh  = q_ws  + (size_t)bh * (L_ * HD_);
  const short* Kh  = k_ws  + (size_t)bh * (L_ * HD_);
  const short* VTh = vt_ws + (size_t)bh * (HD_ * L_);
  const float* mrow = mask + (size_t)b * L_;

  // Q fragments (A-operand): row = lr, k = g*8+j, two hd-halves
  bf16x8 aq0 = *(const bf16x8*)(Qh + (size_t)(qbase + lr) * HD_ + g * 8);
  bf16x8 aq1 = *(const bf16x8*)(Qh + (size_t)(qbase + lr) * HD_ + 32 + g * 8);

  // staging lane constants: 1KB issue = 8 rows x 128B; slot s holds chunk s^row
  int rowin = lane >> 3;
  int sch8 = ((lane & 7) ^ rowin) * 8;   // pre-swizzled source offset (shorts)

  // prologue: stage chunk 0 into buffer 0
#pragma unroll
  for (int j = 0; j < 2; ++j) {
    int e = w * 2 + j, row = e * 8 + rowin;
    gll16(Kh + (size_t)row * HD_ + sch8, lds + e * 1024);
    gll16(VTh + (size_t)row * L_ + sch8, lds + 16384 + e * 1024);
  }
  __syncthreads();

  f32x4 c[4] = {};
  float m[4] = {-1e30f, -1e30f, -1e30f, -1e30f};
  float sum[4] = {0.f, 0.f, 0.f, 0.f};

  for (int ch = 0; ch < 8; ++ch) {
    const char* Kb = lds + (ch & 1) * 8192;
    const char* Vb = lds + 16384 + (ch & 1) * 8192;
    if (ch < 7) {  // issue next chunk's stage first: overlaps this compute
      char* Kn = lds + ((ch + 1) & 1) * 8192;
      char* Vn = lds + 16384 + ((ch + 1) & 1) * 8192;
#pragma unroll
      for (int j = 0; j < 2; ++j) {
        int e = w * 2 + j, row = e * 8 + rowin;
        gll16(Kh + ((size_t)(ch + 1) * 64 + row) * HD_ + sch8, Kn + e * 1024);
        gll16(VTh + (size_t)row * L_ + (ch + 1) * 64 + sch8, Vn + e * 1024);
      }
    }
    float mb[4];
#pragma unroll
    for (int kt = 0; kt < 4; ++kt)
      mb[kt] = (1.0f - mrow[ch * 64 + kt * 16 + lr]) * -1e9f;

    // ---- QK^T for this chunk: s[4] = 16 q-rows x 64 keys ----
    f32x4 s[4];
#pragma unroll
    for (int kt = 0; kt < 4; ++kt) {
      int row = kt * 16 + lr;                      // row & 7 == lr & 7
      bf16x8 bk0 = *(const bf16x8*)(Kb + row * 128 + ((g ^ (lr & 7)) << 4));
      bf16x8 bk1 = *(const bf16x8*)(Kb + row * 128 + (((4 + g) ^ (lr & 7)) << 4));
      f32x4 a = {0.f, 0.f, 0.f, 0.f};
      a = __builtin_amdgcn_mfma_f32_16x16x32_bf16(aq0, bk0, a, 0, 0, 0);
      a = __builtin_amdgcn_mfma_f32_16x16x32_bf16(aq1, bk1, a, 0, 0, 0);
#pragma unroll
      for (int rr = 0; rr < 4; ++rr) a[rr] = a[rr] * 0.125f + mb[kt];
      s[kt] = a;
    }

    // ---- online softmax update (rows g*4+rr; cols lr+16*kt) ----
    float pmax[4], scl[4];
#pragma unroll
    for (int rr = 0; rr < 4; ++rr)
      pmax[rr] = fmaxf(fmaxf(s[0][rr], s[1][rr]), fmaxf(s[2][rr], s[3][rr]));
#pragma unroll
    for (int off = 1; off < 16; off <<= 1)
#pragma unroll
      for (int rr = 0; rr < 4; ++rr)
        pmax[rr] = fmaxf(pmax[rr], __shfl_xor(pmax[rr], off, 64));
#pragma unroll
    for (int rr = 0; rr < 4; ++rr) {
      float mn = fmaxf(m[rr], pmax[rr]);
      scl[rr] = __expf(m[rr] - mn);
      m[rr] = mn;
      sum[rr] *= scl[rr];
    }
#pragma unroll
    for (int nt = 0; nt < 4; ++nt)
#pragma unroll
      for (int rr = 0; rr < 4; ++rr) c[nt][rr] *= scl[rr];

    // P -> wave-private LDS tile (XOR-swizzled rows of 128B)
#pragma unroll
    for (int kt = 0; kt < 4; ++kt) {
      int col2 = (kt * 16 + lr) * 2;
#pragma unroll
      for (int rr = 0; rr < 4; ++rr) {
        float p = __expf(s[kt][rr] - m[rr]);
        sum[rr] += p;
        int row = g * 4 + rr;
        *(short*)(Pl + row * 128 + (col2 ^ ((row & 7) << 4))) = f2bf(p);
      }
    }
    DS_FENCE();   // own-wave P writes visible before transposed reads

    // ---- PV accumulate: c += P(16x64) @ V(64x64) ----
#pragma unroll
    for (int kk = 0; kk < 2; ++kk) {
      bf16x8 ap = *(const bf16x8*)(Pl + lr * 128 +
                                   (((kk * 4 + g) ^ (lr & 7)) << 4));
#pragma unroll
      for (int nt = 0; nt < 4; ++nt) {
        int row = nt * 16 + lr;
        bf16x8 bv = *(const bf16x8*)(Vb + row * 128 +
                                     (((kk * 4 + g) ^ (lr & 7)) << 4));
        c[nt] = __builtin_amdgcn_mfma_f32_16x16x32_bf16(ap, bv, c[nt], 0, 0, 0);
      }
    }
    DS_FENCE();   // P reads drained before next chunk's P writes (WAR)
    if (ch < 7) __syncthreads();   // next staged buffer ready for all waves
  }

  float inv[4];
#pragma unroll
  for (int off = 1; off < 16; off <<= 1)
#pragma unroll
    for (int rr = 0; rr < 4; ++rr) sum[rr] += __shfl_xor(sum[rr], off, 64);
#pragma unroll
  for (int rr = 0; rr < 4; ++rr) inv[rr] = 1.0f / sum[rr];

  // epilogue: ctx_ws[b][l][h][hd] (row-major [16384][512] for the out-GEMM)
#pragma unroll
  for (int nt = 0; nt < 4; ++nt) {
    int hd = nt * 16 + lr;
#pragma unroll
    for (int rr = 0; rr < 4; ++rr) {
      int qrow = qbase + g * 4 + rr;
      ctx_ws[(((size_t)b * L_ + qrow) * H_ + h) * HD_ + hd] =
          f2bf(c[nt][rr] * inv[rr]);
    }
  }
}

// --------------------------------------------------------------------------
// Output GEMM (bf16 x bf16 -> f32), BK=64, global_load_lds, swizzled LDS.
// --------------------------------------------------------------------------
__global__ __launch_bounds__(256) void gemm_out(
    const short* __restrict__ ctx, const short* __restrict__ wt3,
    const float* __restrict__ bO, float* __restrict__ out) {
  __shared__ __align__(16) char lds[32768];
  char* Al = lds;
  char* Bl = lds + 16384;
  int wgid = blockIdx.x + 4 * blockIdx.y;
  int rr_ = wgid >> 3;
  int m0 = ((wgid & 7) * 16 + (rr_ >> 2)) * 128;
  int n0 = (rr_ & 3) * 128;
  int tid = threadIdx.x, lane = tid & 63, w = tid >> 6;
  int wr = w >> 1, wc = w & 1, g = lane >> 4, lr = lane & 15;
  f32x4 acc[4][4] = {};

  for (int k0 = 0; k0 < D_; k0 += 64) {
    __syncthreads();
#pragma unroll
    for (int j = 0; j < 4; ++j) {
      int e = w * 4 + j;
      int row = e * 8 + (lane >> 3);
      int chunk = (lane & 7) ^ (lane >> 3);
      gll16(ctx + (size_t)(m0 + row) * D_ + k0 + chunk * 8, Al + e * 1024);
    }
#pragma unroll
    for (int j = 0; j < 4; ++j) {
      int e = w * 4 + j;
      int row = e * 8 + (lane >> 3);
      int chunk = (lane & 7) ^ (lane >> 3);
      gll16(wt3 + (size_t)(n0 + row) * D_ + k0 + chunk * 8, Bl + e * 1024);
    }
    __syncthreads();
#pragma unroll
    for (int kk = 0; kk < 2; ++kk) {
      bf16x8 af[4], bf_[4];
#pragma unroll
      for (int i = 0; i < 4; ++i) {
        int row = wr * 64 + i * 16 + lr;
        af[i] = *(const bf16x8*)(Al + row * 128 +
                                 (((kk * 4 + g) ^ (lr & 7)) << 4));
      }
#pragma unroll
      for (int i = 0; i < 4; ++i) {
        int row = wc * 64 + i * 16 + lr;
        bf_[i] = *(const bf16x8*)(Bl + row * 128 +
                                  (((kk * 4 + g) ^ (lr & 7)) << 4));
      }
#pragma unroll
      for (int mi = 0; mi < 4; ++mi)
#pragma unroll
        for (int nj = 0; nj < 4; ++nj)
          acc[mi][nj] = __builtin_amdgcn_mfma_f32_16x16x32_bf16(
              af[mi], bf_[nj], acc[mi][nj], 0, 0, 0);
    }
  }
#pragma unroll
  for (int mi = 0; mi < 4; ++mi) {
#pragma unroll
    for (int nj = 0; nj < 4; ++nj) {
      int n = n0 + wc * 64 + nj * 16 + lr;
      float bb = bO[n];
#pragma unroll
      for (int rr = 0; rr < 4; ++rr) {
        int m = m0 + wr * 64 + mi * 16 + g * 4 + rr;
        out[(size_t)m * D_ + n] = acc[mi][nj][rr] + bb;
      }
    }
  }
}

// --------------------------------------------------------------------------
extern "C" void kernel_launch(void* const* d_in, const int* in_sizes, int n_in,
                              void* d_out, int out_size, void* d_ws,
                              size_t ws_size, hipStream_t stream) {
  const float* query = (const float*)d_in[0];
  const float* key   = (const float*)d_in[1];
  const float* value = (const float*)d_in[2];
  const float* mask  = (const float*)d_in[3];
  // d_in[4..8]: edge/path inputs — bias is constant along the softmax axis,
  // so it cancels exactly; unused.
  const float* WQ = (const float*)d_in[9];
  const float* bQ = (const float*)d_in[10];
  const float* WK = (const float*)d_in[11];
  const float* bK = (const float*)d_in[12];
  const float* WV = (const float*)d_in[13];
  const float* bV = (const float*)d_in[14];
  const float* WO = (const float*)d_in[15];
  const float* bO = (const float*)d_in[16];

  short* ws  = (short*)d_ws;
  short* wt  = ws;
  short* q   = ws + 1048576;
  short* k   = q + 8388608;
  short* vt  = k + 8388608;
  short* ctx = vt + 8388608;   // total 34,603,008 shorts = 69.2 MB
  float* out = (float*)d_out;

  wt_kernel<<<dim3(16, 16, 4), 256, 0, stream>>>(WQ, WK, WV, WO, wt);
  gemm_qkv<<<dim3(4, 128, 3), 256, 0, stream>>>(query, key, value, wt,
                                                bQ, bK, bV, q, k, vt);
  attn_kernel<<<2048, 256, 0, stream>>>(q, k, vt, mask, ctx);
  gemm_out<<<dim3(4, 128), 256, 0, stream>>>(ctx, wt + 3 * 262144, bO, out);
}